// Round 1
// baseline (177.186 us; speedup 1.0000x reference)
//
#include <hip/hip_runtime.h>

// MLP3D fused kernel, MI355X gfx950.
// occ = relu(relu(h W1+b1) W2+b2) Wocc + bocc,  h = E(coords) W0 + b0 (no relu)
// cls[p] = relu(h[64p:64p+64] W1[64p:64p+64, 64p:64p+64] + b1[..]) . Wc[p][64p:..] + bc[p]
// Strategy: f16 MFMA 16x16x32, weights pre-transposed to Wt[n][k] f16 in ws.
// GEMMs computed as C' = Wt * act  (weights = A operand, streamed global->VGPR;
// activations = B operand in one LDS buffer). C' rows = out-neurons, cols = points,
// so writeback is contiguous ds_write_b64 per lane (conflict-free with +8 pad).

#define NPTS 131072
#define AST 264   // activation row stride in halves (256 + 8; 16B-aligned rows)

typedef _Float16 half8  __attribute__((ext_vector_type(8)));
typedef _Float16 half4_t __attribute__((ext_vector_type(4)));
typedef float    float4_t __attribute__((ext_vector_type(4)));

__global__ void prep_w0(const float* __restrict__ W0, _Float16* __restrict__ W0t) {
  int id = blockIdx.x * 256 + threadIdx.x;       // 16384 = 256 n * 64 k
  int n = id >> 6, k = id & 63;
  W0t[id] = (k < 63) ? (_Float16)W0[k * 256 + n] : (_Float16)0.f;
}

__global__ void prep_tr(const float* __restrict__ W, _Float16* __restrict__ Wt) {
  __shared__ float tile[32][33];
  int n0 = blockIdx.x * 32, k0 = blockIdx.y * 32;
  int tx = threadIdx.x, ty = threadIdx.y;        // block 32x8
#pragma unroll
  for (int i = 0; i < 32; i += 8)
    tile[ty + i][tx] = W[(k0 + ty + i) * 256 + (n0 + tx)];
  __syncthreads();
#pragma unroll
  for (int i = 0; i < 32; i += 8)
    Wt[(n0 + ty + i) * 256 + (k0 + tx)] = (_Float16)tile[tx][ty + i];
}

// One wave computes C'[64 x 64] = Wt-slice(64 rows) x act(64 points), K = KLEN.
// A-frags (weights) straight from global (L2-resident), B-frags from LDS.
template<int RS, int KLEN>
__device__ __forceinline__ void run_gemm(const _Float16* __restrict__ wbase,
                                         const _Float16* __restrict__ abase,
                                         int c, int q, float4_t acc[4][4]) {
  const _Float16* wp = wbase + c * RS + q * 8;
  const _Float16* ap = abase + c * AST + q * 8;
  half8 a[4], b[4];
#pragma unroll
  for (int tn = 0; tn < 4; ++tn) a[tn] = *(const half8*)(wp + tn * 16 * RS);
#pragma unroll
  for (int tm = 0; tm < 4; ++tm) b[tm] = *(const half8*)(ap + tm * 16 * AST);
#pragma unroll
  for (int kb = 0; kb < KLEN; kb += 32) {
    half8 an[4], bn[4];
    if (kb + 32 < KLEN) {  // compile-time per unrolled iter
#pragma unroll
      for (int tn = 0; tn < 4; ++tn) an[tn] = *(const half8*)(wp + tn * 16 * RS + kb + 32);
#pragma unroll
      for (int tm = 0; tm < 4; ++tm) bn[tm] = *(const half8*)(ap + tm * 16 * AST + kb + 32);
    }
#pragma unroll
    for (int tn = 0; tn < 4; ++tn)
#pragma unroll
      for (int tm = 0; tm < 4; ++tm)
        acc[tn][tm] = __builtin_amdgcn_mfma_f32_16x16x32_f16(a[tn], b[tm], acc[tn][tm], 0, 0, 0);
    if (kb + 32 < KLEN) {
#pragma unroll
      for (int z = 0; z < 4; ++z) { a[z] = an[z]; b[z] = bn[z]; }
    }
  }
}

__global__ __launch_bounds__(256, 2) void mlp_main(
    const float* __restrict__ coords,
    const _Float16* __restrict__ W0t,   // [256][64]
    const _Float16* __restrict__ W1t,   // [256][256]
    const _Float16* __restrict__ W2t,   // [256][256]
    const float* __restrict__ b0, const float* __restrict__ b1,
    const float* __restrict__ b2,
    const float* __restrict__ Wocc, const float* __restrict__ bocc,
    const float* __restrict__ Wc, const float* __restrict__ bc,
    float* __restrict__ out) {
  __shared__ _Float16 actX[64 * AST];   // E -> h -> t1 (one buffer, barriered)
  __shared__ float occ_s[4][64];

  const int t = threadIdx.x;
  const int w = t >> 6;          // wave = out-neuron slice [64w,64w+64) = part id
  const int l = t & 63;
  const int c = l & 15;          // MFMA lane col (row index within A/B frag)
  const int q = l >> 4;          // MFMA quad
  const int m0 = blockIdx.x * 64;

  // ---- positional encoding E into actX[m][0..63] (k=63 zero-padded) ----
  {
    int m = t >> 2, seg = t & 3;
    const float* cp = coords + (size_t)(m0 + m) * 3;
    float x0 = cp[0], x1 = cp[1], x2 = cp[2];
    half8 ev0, ev1;
#pragma unroll
    for (int u = 0; u < 16; ++u) {
      int k = seg * 16 + u;
      float v;
      if (k >= 63) v = 0.f;
      else if (k < 3) v = (k == 0) ? x0 : (k == 1 ? x1 : x2);
      else {
        int kk = k - 3;
        int f = kk / 6;
        int rem = kk - 6 * f;
        int s = (rem >= 3) ? 1 : 0;
        int i = rem - 3 * s;
        float xi = (i == 0) ? x0 : (i == 1 ? x1 : x2);
        float arg = xi * (float)(1 << f);
        // Cody-Waite reduce to [-pi,pi], then fast-path sinf/cosf
        float nn = rintf(arg * 0.15915494309189535f);
        float r = fmaf(nn, -6.28318548202514648f, arg);
        r = fmaf(nn, 1.7484555e-7f, r);
        v = s ? cosf(r) : sinf(r);
      }
      _Float16 hv = (_Float16)v;
      if (u < 8) ev0[u] = hv; else ev1[u - 8] = hv;
    }
    *(half8*)&actX[m * AST + seg * 16] = ev0;
    *(half8*)&actX[m * AST + seg * 16 + 8] = ev1;
  }
  __syncthreads();                                   // (1) E ready

  float4_t acc[4][4];
  const float4_t zero4 = {0.f, 0.f, 0.f, 0.f};

  // ---- layer 0: h = E @ W0 + b0  (no relu) ----
#pragma unroll
  for (int tn = 0; tn < 4; ++tn)
#pragma unroll
    for (int tm = 0; tm < 4; ++tm) acc[tn][tm] = zero4;
  run_gemm<64, 64>(W0t + (size_t)(64 * w) * 64, actX, c, q, acc);
  __syncthreads();                                   // (2) all E reads done
#pragma unroll
  for (int tn = 0; tn < 4; ++tn) {
    float4_t bias = *(const float4_t*)(b0 + 64 * w + tn * 16 + q * 4);
#pragma unroll
    for (int tm = 0; tm < 4; ++tm) {
      float4_t v = acc[tn][tm];
      half4_t hv;
#pragma unroll
      for (int r = 0; r < 4; ++r) hv[r] = (_Float16)(v[r] + bias[r]);
      *(half4_t*)&actX[(tm * 16 + c) * AST + 64 * w + tn * 16 + q * 4] = hv;
    }
  }
  __syncthreads();                                   // (3) h ready

  // ---- part branch p = w: cls from masked 64x64 block of W1 ----
#pragma unroll
  for (int tn = 0; tn < 4; ++tn)
#pragma unroll
    for (int tm = 0; tm < 4; ++tm) acc[tn][tm] = zero4;
  run_gemm<256, 64>(W1t + (size_t)(64 * w) * 256 + 64 * w, actX + 64 * w, c, q, acc);
  {
    float pcls[4] = {0.f, 0.f, 0.f, 0.f};
#pragma unroll
    for (int tn = 0; tn < 4; ++tn) {
      float4_t bias = *(const float4_t*)(b1 + 64 * w + tn * 16 + q * 4);
      float4_t wcv = *(const float4_t*)(Wc + 256 * w + 64 * w + tn * 16 + q * 4);
#pragma unroll
      for (int tm = 0; tm < 4; ++tm) {
        float4_t v = acc[tn][tm];
#pragma unroll
        for (int r = 0; r < 4; ++r) pcls[tm] += fmaxf(v[r] + bias[r], 0.f) * wcv[r];
      }
    }
    float bcw = bc[w];
#pragma unroll
    for (int tm = 0; tm < 4; ++tm) {
      float s = pcls[tm];
      s += __shfl_xor(s, 16, 64);
      s += __shfl_xor(s, 32, 64);
      if (l < 16)
        out[(size_t)NPTS + (size_t)(m0 + tm * 16 + c) * 4 + w] = s + bcw;
    }
  }

  // ---- layer 1: t1 = relu(h @ W1 + b1) ----
#pragma unroll
  for (int tn = 0; tn < 4; ++tn)
#pragma unroll
    for (int tm = 0; tm < 4; ++tm) acc[tn][tm] = zero4;
  run_gemm<256, 256>(W1t + (size_t)(64 * w) * 256, actX, c, q, acc);
  __syncthreads();                                   // (4) all h reads done
#pragma unroll
  for (int tn = 0; tn < 4; ++tn) {
    float4_t bias = *(const float4_t*)(b1 + 64 * w + tn * 16 + q * 4);
#pragma unroll
    for (int tm = 0; tm < 4; ++tm) {
      float4_t v = acc[tn][tm];
      half4_t hv;
#pragma unroll
      for (int r = 0; r < 4; ++r) hv[r] = (_Float16)fmaxf(v[r] + bias[r], 0.f);
      *(half4_t*)&actX[(tm * 16 + c) * AST + 64 * w + tn * 16 + q * 4] = hv;
    }
  }
  __syncthreads();                                   // (5) t1 ready

  // ---- layer 2 + occ head (t2 never materialized) ----
#pragma unroll
  for (int tn = 0; tn < 4; ++tn)
#pragma unroll
    for (int tm = 0; tm < 4; ++tm) acc[tn][tm] = zero4;
  run_gemm<256, 256>(W2t + (size_t)(64 * w) * 256, actX, c, q, acc);
  {
    float pocc[4] = {0.f, 0.f, 0.f, 0.f};
#pragma unroll
    for (int tn = 0; tn < 4; ++tn) {
      float4_t bias = *(const float4_t*)(b2 + 64 * w + tn * 16 + q * 4);
      float4_t wov = *(const float4_t*)(Wocc + 64 * w + tn * 16 + q * 4);
#pragma unroll
      for (int tm = 0; tm < 4; ++tm) {
        float4_t v = acc[tn][tm];
#pragma unroll
        for (int r = 0; r < 4; ++r) pocc[tm] += fmaxf(v[r] + bias[r], 0.f) * wov[r];
      }
    }
#pragma unroll
    for (int tm = 0; tm < 4; ++tm) {
      float s = pocc[tm];
      s += __shfl_xor(s, 16, 64);
      s += __shfl_xor(s, 32, 64);
      if (l < 16) occ_s[w][tm * 16 + c] = s;
    }
  }
  __syncthreads();                                   // (6) occ partials ready
  if (t < 64) {
    float s = occ_s[0][t] + occ_s[1][t] + occ_s[2][t] + occ_s[3][t] + bocc[0];
    out[m0 + t] = s;
  }
}

extern "C" void kernel_launch(void* const* d_in, const int* in_sizes, int n_in,
                              void* d_out, int out_size, void* d_ws, size_t ws_size,
                              hipStream_t stream) {
  const float* coords = (const float*)d_in[0];
  const float* W0   = (const float*)d_in[1];
  const float* b0   = (const float*)d_in[2];
  const float* W1   = (const float*)d_in[3];
  const float* b1   = (const float*)d_in[4];
  const float* W2   = (const float*)d_in[5];
  const float* b2   = (const float*)d_in[6];
  const float* Wocc = (const float*)d_in[7];
  const float* bocc = (const float*)d_in[8];
  const float* Wc   = (const float*)d_in[9];
  const float* bc   = (const float*)d_in[10];
  float* out = (float*)d_out;

  // ws layout: W0t[256][64] f16 (32KB) | W1t[256][256] f16 (128KB) | W2t (128KB)
  _Float16* W0t = (_Float16*)d_ws;
  _Float16* W1t = (_Float16*)((char*)d_ws + 32768);
  _Float16* W2t = (_Float16*)((char*)d_ws + 32768 + 131072);

  prep_w0<<<64, 256, 0, stream>>>(W0, W0t);
  dim3 tb(32, 8);
  prep_tr<<<dim3(8, 8), tb, 0, stream>>>(W1, W1t);
  prep_tr<<<dim3(8, 8), tb, 0, stream>>>(W2, W2t);
  mlp_main<<<NPTS / 64, 256, 0, stream>>>(coords, W0t, W1t, W2t,
                                          b0, b1, b2, Wocc, bocc, Wc, bc, out);
}

// Round 2
// 121.258 us; speedup vs baseline: 1.4612x; 1.4612x over previous
//
#include <hip/hip_runtime.h>

// MLP3D fused, MI355X gfx950 — round 2.
// Changes vs r1: (a) weights pre-swizzled to MFMA-fragment-major layout
// [n-tile][k-block][lane][8] so each A-operand load is one contiguous,
// fully-coalesced 1KB wave load from L2; (b) 128 points/block (halves L2
// weight traffic, doubles MFMA per k-step); (c) 2-deep A prefetch;
// (d) single fused prep kernel (was 3 launches).

#define NPTS 131072
#define M_PB 128
#define AST 264   // activation row stride in halves (256+8; rows 16B aligned, 2-way banks = free)

typedef _Float16 half8   __attribute__((ext_vector_type(8)));
typedef _Float16 half4_t __attribute__((ext_vector_type(4)));
typedef float    float4_t __attribute__((ext_vector_type(4)));

// ---- fused prep: W0/W1/W2 (f32 [K][256]) -> f16 fragment-major in ws ----
// layout: for tile t (16 n), kblock kb (32 k), lane l=(q<<4)|c, j in [0,8):
//   dst[((t*KB + kb)*64 + l)*8 + j] = W[(kb*32 + q*8 + j)*256 + (t*16 + c)]
// W0 is K=63 padded to 64 (KB=2); W1/W2 K=256 (KB=8).
__global__ void prep(const float* __restrict__ W0, const float* __restrict__ W1,
                     const float* __restrict__ W2, _Float16* __restrict__ ws) {
  int id = blockIdx.x * 256 + threadIdx.x;   // 147456 total
  _Float16 v;
  if (id < 16384) {            // W0sw: 16 tiles x 2 kb x 512
    int e = id, j = e & 7, l = (e >> 3) & 63, kb = (e >> 9) & 1, tt = e >> 10;
    int c = l & 15, q = l >> 4;
    int k = kb * 32 + q * 8 + j, n = tt * 16 + c;
    v = (k < 63) ? (_Float16)W0[k * 256 + n] : (_Float16)0.f;
  } else if (id < 81920) {     // W1sw: 16 x 8 x 512
    int e = id - 16384, j = e & 7, l = (e >> 3) & 63, kb = (e >> 9) & 7, tt = e >> 12;
    int c = l & 15, q = l >> 4;
    int k = kb * 32 + q * 8 + j, n = tt * 16 + c;
    v = (_Float16)W1[k * 256 + n];
  } else {                     // W2sw
    int e = id - 81920, j = e & 7, l = (e >> 3) & 63, kb = (e >> 9) & 7, tt = e >> 12;
    int c = l & 15, q = l >> 4;
    int k = kb * 32 + q * 8 + j, n = tt * 16 + c;
    v = (_Float16)W2[k * 256 + n];
  }
  ws[id] = v;
}

// One wave: C'[64n x 128m] += Wsw-slice x act.  A from global (coalesced 1KB
// wave-loads, 2-deep prefetch), B from LDS.
// wb = Wsw + ((w*4)*TOTAL_KB + kb0)*512 + l*8 ; ap = actX + coloff + c*AST + q*8
template<int TOTAL_KB, int KB>
__device__ __forceinline__ void run_gemm(const _Float16* __restrict__ wb,
                                         const _Float16* __restrict__ ap,
                                         float4_t (&acc)[4][8]) {
  half8 a0[4], a1[4];
#pragma unroll
  for (int tn = 0; tn < 4; ++tn) a0[tn] = *(const half8*)(wb + tn * (TOTAL_KB * 512));
  if (KB > 1) {
#pragma unroll
    for (int tn = 0; tn < 4; ++tn) a1[tn] = *(const half8*)(wb + tn * (TOTAL_KB * 512) + 512);
  }
#pragma unroll
  for (int kb = 0; kb < KB; ++kb) {
    half8 b[8];
#pragma unroll
    for (int tm = 0; tm < 8; ++tm) b[tm] = *(const half8*)(ap + tm * 16 * AST + kb * 32);
    half8 an[4];
    if (kb + 2 < KB) {
#pragma unroll
      for (int tn = 0; tn < 4; ++tn)
        an[tn] = *(const half8*)(wb + tn * (TOTAL_KB * 512) + (kb + 2) * 512);
    }
#pragma unroll
    for (int tn = 0; tn < 4; ++tn) {
      half8 acur = (kb & 1) ? a1[tn] : a0[tn];
#pragma unroll
      for (int tm = 0; tm < 8; ++tm)
        acc[tn][tm] = __builtin_amdgcn_mfma_f32_16x16x32_f16(acur, b[tm], acc[tn][tm], 0, 0, 0);
    }
    if (kb + 2 < KB) {
#pragma unroll
      for (int tn = 0; tn < 4; ++tn) {
        if (kb & 1) a1[tn] = an[tn]; else a0[tn] = an[tn];
      }
    }
  }
}

__global__ __launch_bounds__(256, 2) void mlp_main(
    const float* __restrict__ coords,
    const _Float16* __restrict__ W0sw,  // [16][2][64][8]
    const _Float16* __restrict__ W1sw,  // [16][8][64][8]
    const _Float16* __restrict__ W2sw,
    const float* __restrict__ b0, const float* __restrict__ b1,
    const float* __restrict__ b2,
    const float* __restrict__ Wocc, const float* __restrict__ bocc,
    const float* __restrict__ Wc, const float* __restrict__ bc,
    float* __restrict__ out) {
  __shared__ _Float16 actX[M_PB * AST];   // E -> h -> t1 (one buffer, barriered)
  __shared__ float occ_s[4][M_PB];

  const int t = threadIdx.x;
  const int w = t >> 6;          // wave = out-neuron slice [64w,64w+64) = part id
  const int l = t & 63;
  const int c = l & 15;
  const int q = l >> 4;
  const int m0 = blockIdx.x * M_PB;

  // ---- positional encoding E into actX[m][0..63] ----
  // waves 0,1: k 0..31 of all 128 points; waves 2,3: k 32..63 (wave-uniform kh)
  {
    int m = t & 127, kh = (t >> 7) * 32;
    const float* cp = coords + (size_t)(m0 + m) * 3;
    float x0 = cp[0], x1 = cp[1], x2 = cp[2];
#pragma unroll
    for (int i = 0; i < 4; ++i) {
      half8 ev;
#pragma unroll
      for (int u = 0; u < 8; ++u) {
        int k = kh + i * 8 + u;
        float v;
        if (k >= 63) v = 0.f;
        else if (k < 3) v = (k == 0) ? x0 : (k == 1 ? x1 : x2);
        else {
          int kk = k - 3;
          int f = kk / 6;
          int rem = kk - 6 * f;
          int s = (rem >= 3) ? 1 : 0;
          int i3 = rem - 3 * s;
          float xi = (i3 == 0) ? x0 : (i3 == 1 ? x1 : x2);
          float arg = xi * (float)(1 << f);
          float nn = rintf(arg * 0.15915494309189535f);
          float r = fmaf(nn, -6.28318548202514648f, arg);
          r = fmaf(nn, 1.7484555e-7f, r);
          v = s ? __cosf(r) : __sinf(r);
        }
        ev[u] = (_Float16)v;
      }
      *(half8*)&actX[m * AST + kh + i * 8] = ev;
    }
  }
  __syncthreads();                                   // (1) E ready

  float4_t acc[4][8];
  const float4_t zero4 = {0.f, 0.f, 0.f, 0.f};
  const _Float16* apc = actX + c * AST + q * 8;

  // ---- layer 0: h = E @ W0 + b0 (no relu) ----
#pragma unroll
  for (int tn = 0; tn < 4; ++tn)
#pragma unroll
    for (int tm = 0; tm < 8; ++tm) acc[tn][tm] = zero4;
  run_gemm<2, 2>(W0sw + (w * 4) * 2 * 512 + l * 8, apc, acc);
  __syncthreads();                                   // (2) all E reads done
#pragma unroll
  for (int tn = 0; tn < 4; ++tn) {
    float4_t bias = *(const float4_t*)(b0 + 64 * w + tn * 16 + q * 4);
#pragma unroll
    for (int tm = 0; tm < 8; ++tm) {
      float4_t v = acc[tn][tm];
      half4_t hv;
#pragma unroll
      for (int r = 0; r < 4; ++r) hv[r] = (_Float16)(v[r] + bias[r]);
      *(half4_t*)&actX[(tm * 16 + c) * AST + 64 * w + tn * 16 + q * 4] = hv;
    }
  }
  __syncthreads();                                   // (3) h ready

  // ---- part branch p = w: masked 64x64 block of W1 (k range [64w,64w+64)) ----
#pragma unroll
  for (int tn = 0; tn < 4; ++tn)
#pragma unroll
    for (int tm = 0; tm < 8; ++tm) acc[tn][tm] = zero4;
  run_gemm<8, 2>(W1sw + ((w * 4) * 8 + 2 * w) * 512 + l * 8, apc + 64 * w, acc);
  {
    float pcls[8] = {0.f, 0.f, 0.f, 0.f, 0.f, 0.f, 0.f, 0.f};
#pragma unroll
    for (int tn = 0; tn < 4; ++tn) {
      float4_t bias = *(const float4_t*)(b1 + 64 * w + tn * 16 + q * 4);
      float4_t wcv = *(const float4_t*)(Wc + 256 * w + 64 * w + tn * 16 + q * 4);
#pragma unroll
      for (int tm = 0; tm < 8; ++tm) {
        float4_t v = acc[tn][tm];
#pragma unroll
        for (int r = 0; r < 4; ++r) pcls[tm] += fmaxf(v[r] + bias[r], 0.f) * wcv[r];
      }
    }
    float bcw = bc[w];
#pragma unroll
    for (int tm = 0; tm < 8; ++tm) {
      float s = pcls[tm];
      s += __shfl_xor(s, 16, 64);
      s += __shfl_xor(s, 32, 64);
      if (l < 16)
        out[(size_t)NPTS + (size_t)(m0 + tm * 16 + c) * 4 + w] = s + bcw;
    }
  }

  // ---- layer 1: t1 = relu(h @ W1 + b1) ----
#pragma unroll
  for (int tn = 0; tn < 4; ++tn)
#pragma unroll
    for (int tm = 0; tm < 8; ++tm) acc[tn][tm] = zero4;
  run_gemm<8, 8>(W1sw + (w * 4) * 8 * 512 + l * 8, apc, acc);
  __syncthreads();                                   // (4) all h reads done
#pragma unroll
  for (int tn = 0; tn < 4; ++tn) {
    float4_t bias = *(const float4_t*)(b1 + 64 * w + tn * 16 + q * 4);
#pragma unroll
    for (int tm = 0; tm < 8; ++tm) {
      float4_t v = acc[tn][tm];
      half4_t hv;
#pragma unroll
      for (int r = 0; r < 4; ++r) hv[r] = (_Float16)fmaxf(v[r] + bias[r], 0.f);
      *(half4_t*)&actX[(tm * 16 + c) * AST + 64 * w + tn * 16 + q * 4] = hv;
    }
  }
  __syncthreads();                                   // (5) t1 ready

  // ---- layer 2 + occ head (t2 never materialized) ----
#pragma unroll
  for (int tn = 0; tn < 4; ++tn)
#pragma unroll
    for (int tm = 0; tm < 8; ++tm) acc[tn][tm] = zero4;
  run_gemm<8, 8>(W2sw + (w * 4) * 8 * 512 + l * 8, apc, acc);
  {
    float pocc[8] = {0.f, 0.f, 0.f, 0.f, 0.f, 0.f, 0.f, 0.f};
#pragma unroll
    for (int tn = 0; tn < 4; ++tn) {
      float4_t bias = *(const float4_t*)(b2 + 64 * w + tn * 16 + q * 4);
      float4_t wov = *(const float4_t*)(Wocc + 64 * w + tn * 16 + q * 4);
#pragma unroll
      for (int tm = 0; tm < 8; ++tm) {
        float4_t v = acc[tn][tm];
#pragma unroll
        for (int r = 0; r < 4; ++r) pocc[tm] += fmaxf(v[r] + bias[r], 0.f) * wov[r];
      }
    }
#pragma unroll
    for (int tm = 0; tm < 8; ++tm) {
      float s = pocc[tm];
      s += __shfl_xor(s, 16, 64);
      s += __shfl_xor(s, 32, 64);
      if (l < 16) occ_s[w][tm * 16 + c] = s;
    }
  }
  __syncthreads();                                   // (6) occ partials ready
  if (t < M_PB) {
    out[m0 + t] = occ_s[0][t] + occ_s[1][t] + occ_s[2][t] + occ_s[3][t] + bocc[0];
  }
}

extern "C" void kernel_launch(void* const* d_in, const int* in_sizes, int n_in,
                              void* d_out, int out_size, void* d_ws, size_t ws_size,
                              hipStream_t stream) {
  const float* coords = (const float*)d_in[0];
  const float* W0   = (const float*)d_in[1];
  const float* b0   = (const float*)d_in[2];
  const float* W1   = (const float*)d_in[3];
  const float* b1   = (const float*)d_in[4];
  const float* W2   = (const float*)d_in[5];
  const float* b2   = (const float*)d_in[6];
  const float* Wocc = (const float*)d_in[7];
  const float* bocc = (const float*)d_in[8];
  const float* Wc   = (const float*)d_in[9];
  const float* bc   = (const float*)d_in[10];
  float* out = (float*)d_out;

  _Float16* ws = (_Float16*)d_ws;       // W0sw[16384] | W1sw[65536] | W2sw[65536]
  _Float16* W0sw = ws;
  _Float16* W1sw = ws + 16384;
  _Float16* W2sw = ws + 81920;

  prep<<<576, 256, 0, stream>>>(W0, W1, W2, ws);
  mlp_main<<<NPTS / M_PB, 256, 0, stream>>>(coords, W0sw, W1sw, W2sw,
                                            b0, b1, b2, Wocc, bocc, Wc, bc, out);
}